// Round 5
// baseline (5321.224 us; speedup 1.0000x reference)
//
#include <hip/hip_runtime.h>
#include <hip/hip_cooperative_groups.h>
namespace cg = cooperative_groups;

#define N_ENT   250002
#define DD      128
#define T_STEPS 16
#define E_EDGES 300000
#define S_SEEDS 256
#define C_NUM   50000
#define BASE    200000          // user_id_max + 1
#define NB      245             // scan blocks per step (245*1024 = 250880 >= N_ENT)
#define N_PAD   (NB * 1024)     // padded per-step offs row
#define NBKT    245             // dst buckets per step (dst >> 10), 245*1024 = N_PAD
#define BSH     10
#define CAPB    1536            // bucket capacity (mean 1229, sigma ~35 -> 8.8 sigma)
#define EPB     2048            // edges per bucketA block
#define NGRID16 ((N_ENT + 15) / 16)      // 15626 node blocks (16 nodes/block, 4/wave)
#define SEED16  (5 * S_SEEDS / 16)       // 80 seed-snapshot blocks
#define NCG     3125                     // column 16-groups (50000/16)
#define SCHUNK  49                       // colgroups per score chunk (64 chunks)

typedef __attribute__((ext_vector_type(8))) short short8;
typedef __attribute__((ext_vector_type(4))) float f32x4;

__device__ inline unsigned short f2bf(float f) {
    unsigned u = __float_as_uint(f);
    u += 0x7FFFu + ((u >> 16) & 1u);          // RNE
    return (unsigned short)(u >> 16);
}
__device__ inline float bf_lo(unsigned p) { return __uint_as_float(p << 16); }
__device__ inline float bf_hi(unsigned p) { return __uint_as_float(p & 0xffff0000u); }
__device__ inline unsigned pk2(float x, float y) {
    return (unsigned)f2bf(x) | ((unsigned)f2bf(y) << 16);
}

// ---------------- init: node_bf <- bf16(ent); zero gcount/rowsum/out ----------------
#define NODE_W (N_ENT * 64)          // 16,000,128 unsigned (2 bf16 each)
#define GC_W   (T_STEPS * NBKT)      // 3,920 bucket counters
__global__ __launch_bounds__(256) void init_kernel(
    const float2* __restrict__ ent2, unsigned* __restrict__ node_bf,
    int* __restrict__ gcount, float* __restrict__ rowsum, float* __restrict__ out)
{
    int gid = blockIdx.x * 256 + threadIdx.x;
    if (gid < NODE_W) {
        float2 v = ent2[gid];
        node_bf[gid] = pk2(v.x, v.y);
    } else if (gid < NODE_W + GC_W) {
        gcount[gid - NODE_W] = 0;
    } else if (gid < NODE_W + GC_W + T_STEPS * S_SEEDS) {
        rowsum[gid - NODE_W - GC_W] = 0.f;
    } else if (gid == NODE_W + GC_W + T_STEPS * S_SEEDS) {
        out[0] = 0.f;
    }
}

// ---------------- convert all_c to bf16 (from pristine ent) ----------------
__global__ __launch_bounds__(256) void conv_kernel(
    const float4* __restrict__ c4, ushort4* __restrict__ cb4)
{
    int gid = blockIdx.x * 256 + threadIdx.x;    // C_NUM*128/4 = 1,600,000
    float4 v = c4[gid];
    cb4[gid] = make_ushort4(f2bf(v.x), f2bf(v.y), f2bf(v.z), f2bf(v.w));
}

// ---------------- CSR build A: bucketize edges by dst>>10 (dense chunk writes) ----------------
// entry = (src | rel<<18) | (dst_low10 << 22)
__global__ __launch_bounds__(256) void bucketA(
    const int* __restrict__ esrc, const int* __restrict__ edst, const int* __restrict__ erel,
    int* __restrict__ gcount, unsigned* __restrict__ bkt)
{
    int t = blockIdx.y;
    int base = blockIdx.x * EPB;
    int tid = threadIdx.x;
    __shared__ int lcnt[NBKT];
    __shared__ int lbase[NBKT];
    for (int i = tid; i < NBKT; i += 256) lcnt[i] = 0;
    __syncthreads();
    int dl[8], sr[8], off[8], bk[8];
    #pragma unroll
    for (int i = 0; i < 8; ++i) {
        int e = base + i * 256 + tid;
        bk[i] = -1;
        if (e < E_EDGES) {
            int eb = t * E_EDGES + e;
            int dd = edst[eb];
            sr[i] = esrc[eb] | (erel[eb] << 18);
            dl[i] = dd & ((1 << BSH) - 1);
            bk[i] = dd >> BSH;
            off[i] = atomicAdd(&lcnt[bk[i]], 1);
        }
    }
    __syncthreads();
    for (int i = tid; i < NBKT; i += 256)
        lbase[i] = atomicAdd(&gcount[t * NBKT + i], lcnt[i]);
    __syncthreads();
    #pragma unroll
    for (int i = 0; i < 8; ++i) {
        if (bk[i] >= 0) {
            int pos = lbase[bk[i]] + off[i];
            if (pos < CAPB)
                bkt[((size_t)(t * NBKT + bk[i])) * CAPB + pos] =
                    (unsigned)sr[i] | ((unsigned)dl[i] << 22);
        }
    }
}

// ---------------- CSR build B1: per-bucket LDS histogram -> offs counts + block partial ----------------
__global__ __launch_bounds__(256) void histB(
    const int* __restrict__ gcount, const unsigned* __restrict__ bkt,
    int* __restrict__ offs, int* __restrict__ partials)
{
    int b = blockIdx.x, t = blockIdx.y, tid = threadIdx.x;
    __shared__ int cnt[1024];
    for (int i = tid; i < 1024; i += 256) cnt[i] = 0;
    __syncthreads();
    int n = min(gcount[t * NBKT + b], CAPB);
    const unsigned* bp = bkt + ((size_t)(t * NBKT + b)) * CAPB;
    for (int i = tid; i < n; i += 256)
        atomicAdd(&cnt[bp[i] >> 22], 1);
    __syncthreads();
    int* op = offs + (size_t)t * N_PAD + (b << BSH);
    for (int i = tid; i < 1024; i += 256) op[i] = cnt[i];
    if (tid == 0) partials[t * NB + b] = n;
}

// ---------------- version-bit build: vb[t][n] = buffer holding n's value at START of step t ----
__global__ __launch_bounds__(256) void vb_build(
    const int* __restrict__ offs, unsigned char* __restrict__ vbarr)
{
    int n = blockIdx.x * 256 + threadIdx.x;
    if (n >= N_ENT) return;
    int v = 0;
    #pragma unroll
    for (int t = 0; t < T_STEPS; ++t) {
        vbarr[(size_t)t * N_ENT + n] = (unsigned char)v;
        v ^= (offs[(size_t)t * N_PAD + n] > 0) ? 1 : 0;
    }
}

// ---------------- CSR build 2b: exclusive scan of partials per step ----------------
__global__ __launch_bounds__(256) void scanB_kernel(int* __restrict__ partials)
{
    __shared__ int sc[256];
    int t = blockIdx.x, tid = threadIdx.x;
    int v = (tid < NB) ? partials[t * NB + tid] : 0;
    sc[tid] = v;
    __syncthreads();
    for (int off = 1; off < 256; off <<= 1) {
        int y = (tid >= off) ? sc[tid - off] : 0;
        __syncthreads();
        sc[tid] += y;
        __syncthreads();
    }
    if (tid < NB) partials[t * NB + tid] = (tid > 0) ? sc[tid - 1] : 0;
}

// ---------------- CSR build 2c: block-local exclusive scan + block prefix ----------------
__global__ __launch_bounds__(256) void scanC_kernel(
    int* __restrict__ offs, const int* __restrict__ partials)
{
    int t = blockIdx.y, b = blockIdx.x, tid = threadIdx.x;
    int* base = offs + (size_t)t * N_PAD + b * 1024 + tid * 4;
    int4 v = *(const int4*)base;
    int s = v.x + v.y + v.z + v.w;
    int lane = tid & 63, wv = tid >> 6;
    int x = s;                               // inclusive wave scan
    #pragma unroll
    for (int off = 1; off < 64; off <<= 1) {
        int y = __shfl_up(x, off, 64);
        if (lane >= off) x += y;
    }
    __shared__ int wsum[4];
    if (lane == 63) wsum[wv] = x;
    __syncthreads();
    int prefix = partials[t * NB + b];
    for (int w = 0; w < 4; ++w) prefix += (w < wv) ? wsum[w] : 0;
    int excl = prefix + x - s;               // exclusive of this thread's 4 elems
    int4 o;
    o.x = excl; o.y = o.x + v.x; o.z = o.y + v.y; o.w = o.z + v.z;
    *(int4*)base = o;
}

// ---------------- CSR build B2: per-bucket scatter into L2-local CSR window ----------------
// sortedp entry: src | rel<<18 | vb(src,t)<<22
__global__ __launch_bounds__(256) void scatB(
    const int* __restrict__ gcount, const unsigned* __restrict__ bkt,
    const int* __restrict__ offs, const unsigned char* __restrict__ vbarr,
    unsigned* __restrict__ sortedp)
{
    int b = blockIdx.x, t = blockIdx.y, tid = threadIdx.x;
    __shared__ int cur[1024];
    const int* op = offs + (size_t)t * N_PAD + (b << BSH);
    for (int i = tid; i < 1024; i += 256) cur[i] = op[i];
    __syncthreads();
    int n = min(gcount[t * NBKT + b], CAPB);
    const unsigned* bp = bkt + ((size_t)(t * NBKT + b)) * CAPB;
    unsigned* sp = sortedp + (size_t)t * E_EDGES;
    const unsigned char* vbt = vbarr + (size_t)t * N_ENT;
    for (int i = tid; i < n; i += 256) {
        unsigned e = bp[i];
        int pos = atomicAdd(&cur[e >> 22], 1);
        sp[pos] = (e & 0x3FFFFFu) | ((unsigned)vbt[e & 0x3FFFFu] << 22);
    }
}

// ---------------- gather step body (shared by persistent + fallback) ----------------
__device__ __forceinline__ void gather_body(
    unsigned* node0, unsigned* node1, const float2* rel2, const int* op,
    const unsigned* sp, const int* seeds, const unsigned char* vbarr,
    float2* gath2, int t, int bx, int wv, int grp, int l16)
{
    int n = 0, gslot = -1;
    bool active;
    if (bx < NGRID16) {
        n = bx * 16 + wv * 4 + grp;
        active = (n < N_ENT);
    } else {
        int g = (bx - NGRID16) * 16 + wv * 4 + grp;   // 0..1279
        int j = g >> 8;
        active = (t + j < T_STEPS);
        if (active) {
            n = seeds[t * S_SEEDS + g];               // == seeds[(t+j)*256 + (g&255)]
            gslot = (((t + j) * 5 + (4 - j)) * S_SEEDS + (g & 255)) * 64 + l16 * 4;
        }
    }
    if (!active) return;
    int start = op[n];
    int end = op[n + 1];
    if (end == start && gslot < 0) return;           // untouched node: no copy needed
    int vb = vbarr[(size_t)t * N_ENT + n];
    const unsigned* selfb = vb ? node1 : node0;
    uint4 nb = *((const uint4*)(selfb + (size_t)n * 64) + l16);
    float vx0 = bf_lo(nb.x), vy0 = bf_hi(nb.x);
    float vx1 = bf_lo(nb.y), vy1 = bf_hi(nb.y);
    float vx2 = bf_lo(nb.z), vy2 = bf_hi(nb.z);
    float vx3 = bf_lo(nb.w), vy3 = bf_hi(nb.w);
    if (end > start) {
        float ax0=0.f,ay0=0.f,ax1=0.f,ay1=0.f,ax2=0.f,ay2=0.f,ax3=0.f,ay3=0.f;
        for (int p = start; p < end; ++p) {
            unsigned pr = sp[p];
            const unsigned* gb = (pr & (1u << 22)) ? node1 : node0;
            uint4 sb = *((const uint4*)(gb + (size_t)(pr & 0x3FFFFu) * 64) + l16);
            const float* rp = (const float*)(rel2 + ((pr >> 18) & 15u) * 64) + l16 * 8;
            float4 r01 = *(const float4*)rp;
            float4 r23 = *(const float4*)(rp + 4);
            ax0 += bf_lo(sb.x) * r01.x; ay0 += bf_hi(sb.x) * r01.y;
            ax1 += bf_lo(sb.y) * r01.z; ay1 += bf_hi(sb.y) * r01.w;
            ax2 += bf_lo(sb.z) * r23.x; ay2 += bf_hi(sb.z) * r23.y;
            ax3 += bf_lo(sb.w) * r23.z; ay3 += bf_hi(sb.w) * r23.w;
        }
        float inv = 1.0f / (float)(end - start);
        vx0 += ax0 * inv; vy0 += ay0 * inv;
        vx1 += ax1 * inv; vy1 += ay1 * inv;
        vx2 += ax2 * inv; vy2 += ay2 * inv;
        vx3 += ax3 * inv; vy3 += ay3 * inv;
    }
    uint4 o;
    o.x = pk2(vx0, vy0); o.y = pk2(vx1, vy1);
    o.z = pk2(vx2, vy2); o.w = pk2(vx3, vy3);
    if (gslot >= 0) {
        gath2[gslot + 0] = make_float2(bf_lo(o.x), bf_hi(o.x));
        gath2[gslot + 1] = make_float2(bf_lo(o.y), bf_hi(o.y));
        gath2[gslot + 2] = make_float2(bf_lo(o.z), bf_hi(o.z));
        gath2[gslot + 3] = make_float2(bf_lo(o.w), bf_hi(o.w));
    } else {
        unsigned* outb = vb ? node0 : node1;
        *((uint4*)(outb + (size_t)n * 64) + l16) = o;
    }
}

// ---------------- persistent cooperative gather: all 16 steps, grid.sync between ----------------
__global__ __launch_bounds__(256, 4) void gather_persist(
    unsigned* node0, unsigned* node1, const float2* rel2, const int* offs,
    const unsigned* sortedp, const int* seeds, const unsigned char* vbarr,
    float2* gath2)
{
    cg::grid_group grid = cg::this_grid();
    int wv = threadIdx.x >> 6;
    int lane = threadIdx.x & 63;
    int grp = lane >> 4;
    int l16 = lane & 15;
    for (int t = 0; t < T_STEPS; ++t) {
        const int* op = offs + (size_t)t * N_PAD;
        const unsigned* sp = sortedp + (size_t)t * E_EDGES;
        for (int bx = blockIdx.x; bx < NGRID16 + SEED16; bx += (int)gridDim.x)
            gather_body(node0, node1, rel2, op, sp, seeds, vbarr, gath2,
                        t, bx, wv, grp, l16);
        __threadfence();
        grid.sync();
    }
}

// ---------------- fallback per-step gather (if cooperative launch unavailable) ----------------
__global__ __launch_bounds__(256) void gather_fused(
    unsigned* node0, unsigned* node1, const float2* rel2, const int* offs,
    const unsigned* sortedp, const int* seeds, const unsigned char* vbarr,
    float2* gath2, int t)
{
    int wv = threadIdx.x >> 6;
    int lane = threadIdx.x & 63;
    gather_body(node0, node1, rel2, offs + (size_t)t * N_PAD,
                sortedp + (size_t)t * E_EDGES, seeds, vbarr, gath2,
                t, blockIdx.x, wv, lane >> 4, lane & 15);
}

// ---------------- 5-snapshot attention per (t,s): one wave each; writes u fp32 + bf16 ----------------
__global__ __launch_bounds__(64) void attn_kernel(
    const float2* __restrict__ q2, const float2* __restrict__ g2,
    const int* __restrict__ seeds, float2* __restrict__ u2, unsigned* __restrict__ ubf)
{
    int b = blockIdx.x;          // 4096 = T*S
    int t = b >> 8;
    int s = b & 255;
    int lane = threadIdx.x;
    int seed = seeds[t * S_SEEDS + s];
    float2 q = q2[seed * 64 + lane];
    float2 g[5];
    float att[5];
    #pragma unroll
    for (int w = 0; w < 5; ++w) {
        float2 gv = g2[((t * 5 + w) * S_SEEDS + s) * 64 + lane];
        g[w] = gv;
        float p = gv.x * q.x + gv.y * q.y;
        #pragma unroll
        for (int off = 32; off > 0; off >>= 1) p += __shfl_xor(p, off, 64);
        att[w] = (w >= 4 - t) ? p : -1e9f;   // invalid slots masked -> weight exactly 0
    }
    float m = -1e30f;
    #pragma unroll
    for (int w = 0; w < 5; ++w) m = fmaxf(m, att[w]);
    float den = 0.f;
    #pragma unroll
    for (int w = 0; w < 5; ++w) den += __expf(att[w] - m);
    float invd = 1.0f / den;
    float2 o = make_float2(0.f, 0.f);
    #pragma unroll
    for (int w = 0; w < 5; ++w) {
        float wt = __expf(att[w] - m) * invd;
        o.x += wt * g[w].x;
        o.y += wt * g[w].y;
    }
    int idx = (t * S_SEEDS + s) * 64 + lane;
    u2[idx] = o;
    ubf[idx] = pk2(o.x, o.y);
}

// ---------------- transposed-accumulate MFMA score GEMM + streaming sum(exp) ----------------
// A-operand = cb columns (M dim), B-operand = ub rows (N dim = lane&15, FIXED per lane).
// Lane accumulates sum_r expf(d[r]) privately -> no cross-lane/LDS in the loop.
// Wave holds 4 row-sets (64 rows); block = 4 waves = 256 rows; 16 row-blocks x 64 chunks.
// XCD swizzle: all 16 row-blocks of a chunk land on one XCD -> chunk (200 KB) L2-resident.
__global__ __launch_bounds__(256) void score_mfma(
    const unsigned short* __restrict__ ub, const unsigned short* __restrict__ cb,
    float* __restrict__ rowsum)
{
    int tid = threadIdx.x;
    int wv = tid >> 6, lane = tid & 63;
    int col16 = lane & 15, quad = lane >> 4;
    int b = blockIdx.x;                 // 0..1023
    int xcd = b & 7, k = b >> 3;
    int ychunk = xcd + 8 * (k >> 4);    // 0..63, ychunk%8 == xcd
    int xblk = k & 15;                  // 0..15
    int rbase = xblk * 256 + wv * 64;

    short8 B[4][4];                     // 4 row-sets x 4 K-slices (ub register-resident)
    #pragma unroll
    for (int s = 0; s < 4; ++s) {
        const unsigned short* bp = ub + (size_t)(rbase + s * 16 + col16) * DD + quad * 8;
        #pragma unroll
        for (int kk = 0; kk < 4; ++kk) B[s][kk] = *(const short8*)(bp + kk * 32);
    }

    float acc0 = 0.f, acc1 = 0.f, acc2 = 0.f, acc3 = 0.f;
    int c0 = ychunk * SCHUNK;
    int c1 = min(c0 + SCHUNK, NCG);
    const unsigned short* abase = cb + col16 * DD + quad * 8;   // + c*2048

#define SCORE_STEP(AF)  do {                                                              \
        f32x4 d0 = {0.f,0.f,0.f,0.f}, d1 = {0.f,0.f,0.f,0.f};                             \
        f32x4 d2 = {0.f,0.f,0.f,0.f}, d3 = {0.f,0.f,0.f,0.f};                             \
        _Pragma("unroll")                                                                 \
        for (int kk = 0; kk < 4; ++kk) {                                                  \
            d0 = __builtin_amdgcn_mfma_f32_16x16x32_bf16(AF[kk], B[0][kk], d0, 0, 0, 0);  \
            d1 = __builtin_amdgcn_mfma_f32_16x16x32_bf16(AF[kk], B[1][kk], d1, 0, 0, 0);  \
            d2 = __builtin_amdgcn_mfma_f32_16x16x32_bf16(AF[kk], B[2][kk], d2, 0, 0, 0);  \
            d3 = __builtin_amdgcn_mfma_f32_16x16x32_bf16(AF[kk], B[3][kk], d3, 0, 0, 0);  \
        }                                                                                 \
        _Pragma("unroll")                                                                 \
        for (int r = 0; r < 4; ++r) {                                                     \
            acc0 += __expf(d0[r]); acc1 += __expf(d1[r]);                                 \
            acc2 += __expf(d2[r]); acc3 += __expf(d3[r]);                                 \
        } } while (0)

    short8 A0[4], A1[4];
    #pragma unroll
    for (int kk = 0; kk < 4; ++kk)
        A0[kk] = *(const short8*)(abase + (size_t)c0 * 2048 + kk * 32);
    int c = c0;
    for (; c + 2 <= c1; c += 2) {
        #pragma unroll
        for (int kk = 0; kk < 4; ++kk)
            A1[kk] = *(const short8*)(abase + (size_t)(c + 1) * 2048 + kk * 32);
        SCORE_STEP(A0);
        if (c + 2 < c1) {
            #pragma unroll
            for (int kk = 0; kk < 4; ++kk)
                A0[kk] = *(const short8*)(abase + (size_t)(c + 2) * 2048 + kk * 32);
        }
        SCORE_STEP(A1);
    }
    if (c < c1) SCORE_STEP(A0);

    acc0 += __shfl_xor(acc0, 16, 64); acc0 += __shfl_xor(acc0, 32, 64);
    acc1 += __shfl_xor(acc1, 16, 64); acc1 += __shfl_xor(acc1, 32, 64);
    acc2 += __shfl_xor(acc2, 16, 64); acc2 += __shfl_xor(acc2, 32, 64);
    acc3 += __shfl_xor(acc3, 16, 64); acc3 += __shfl_xor(acc3, 32, 64);
    if (quad == 0) {
        atomicAdd(&rowsum[rbase +  0 + col16], acc0);
        atomicAdd(&rowsum[rbase + 16 + col16], acc1);
        atomicAdd(&rowsum[rbase + 32 + col16], acc2);
        atomicAdd(&rowsum[rbase + 48 + col16], acc3);
    }
}

// ---------------- final: loss = sum(log(rowsum) - pos), pos in fp32 ----------------
__global__ __launch_bounds__(256) void final_kernel(
    const float2* __restrict__ u2, const float* __restrict__ ent,
    const int* __restrict__ cidx, const float* __restrict__ rowsum,
    float* __restrict__ out)
{
    int wv = threadIdx.x >> 6, lane = threadIdx.x & 63;
    int row = blockIdx.x * 4 + wv;       // grid 1024 -> 4096 rows
    int ci = cidx[row];
    const float2* tp = (const float2*)(ent + (size_t)(BASE + ci) * DD);
    float2 a = u2[row * 64 + lane];
    float2 t = tp[lane];
    float p = a.x * t.x + a.y * t.y;
    #pragma unroll
    for (int off = 32; off > 0; off >>= 1) p += __shfl_xor(p, off, 64);
    if (lane == 0) atomicAdd(out, logf(rowsum[row]) - p);
}

extern "C" void kernel_launch(void* const* d_in, const int* in_sizes, int n_in,
                              void* d_out, int out_size, void* d_ws, size_t ws_size,
                              hipStream_t stream)
{
    (void)in_sizes; (void)n_in; (void)out_size; (void)ws_size;
    const float* ent   = (const float*)d_in[0];
    const float* query = (const float*)d_in[1];
    const float* rel   = (const float*)d_in[2];
    const int* esrc    = (const int*)d_in[3];
    const int* edst    = (const int*)d_in[4];
    const int* erel    = (const int*)d_in[5];
    const int* seeds   = (const int*)d_in[6];
    const int* cidx    = (const int*)d_in[7];
    float* out = (float*)d_out;

    // ws: node0 | node1 | offs | partials | gcount | bkt | sortedp | vbarr | gath | u | ubf | cb | rowsum
    char* ws = (char*)d_ws;
    size_t off = 0;
    unsigned* node0   = (unsigned*)(ws + off);       off += (size_t)N_ENT * DD * 2;            // 64.0 MB
    unsigned* node1   = (unsigned*)(ws + off);       off += (size_t)N_ENT * DD * 2;            // 64.0 MB
    int*      offs    = (int*)(ws + off);            off += (size_t)T_STEPS * N_PAD * 4;       // 16.1 MB
    int*      partials= (int*)(ws + off);            off += (size_t)T_STEPS * NB * 4;          // 15.7 KB
    int*      gcount  = (int*)(ws + off);            off += (size_t)T_STEPS * NBKT * 4;        // 15.7 KB
    unsigned* bkt     = (unsigned*)(ws + off);       off += (size_t)T_STEPS * NBKT * CAPB * 4; // 24.1 MB
    unsigned* sortedp = (unsigned*)(ws + off);       off += (size_t)T_STEPS * E_EDGES * 4;     // 19.2 MB
    unsigned char* vbarr = (unsigned char*)(ws + off); off += (size_t)T_STEPS * N_ENT;         //  4.0 MB
    float*    gath    = (float*)(ws + off);          off += (size_t)T_STEPS * 5 * S_SEEDS * DD * 4;
    float*    u       = (float*)(ws + off);          off += (size_t)T_STEPS * S_SEEDS * DD * 4;
    unsigned* ubf     = (unsigned*)(ws + off);       off += (size_t)T_STEPS * S_SEEDS * DD * 2;
    unsigned short* cb = (unsigned short*)(ws + off); off += (size_t)C_NUM * DD * 2;
    float*    rsum    = (float*)(ws + off);          off += (size_t)T_STEPS * S_SEEDS * 4;

    int init_items = NODE_W + GC_W + T_STEPS * S_SEEDS + 1;
    init_kernel<<<(init_items + 255) / 256, 256, 0, stream>>>(
        (const float2*)ent, node0, gcount, rsum, out);
    conv_kernel<<<C_NUM * DD / 4 / 256, 256, 0, stream>>>(
        (const float4*)(ent + (size_t)BASE * DD), (ushort4*)cb);

    dim3 bgrid((E_EDGES + EPB - 1) / EPB, T_STEPS);   // (147, 16)
    dim3 kgrid(NBKT, T_STEPS);                        // (245, 16)
    bucketA<<<bgrid, 256, 0, stream>>>(esrc, edst, erel, gcount, bkt);
    histB<<<kgrid, 256, 0, stream>>>(gcount, bkt, offs, partials);
    vb_build<<<(N_ENT + 255) / 256, 256, 0, stream>>>(offs, vbarr);
    scanB_kernel<<<T_STEPS, 256, 0, stream>>>(partials);
    scanC_kernel<<<kgrid, 256, 0, stream>>>(offs, partials);
    scatB<<<kgrid, 256, 0, stream>>>(gcount, bkt, offs, vbarr, sortedp);

    // persistent cooperative gather (16 steps, grid.sync between); fallback: 16 launches
    const float2* relp = (const float2*)rel;
    float2* gathp = (float2*)gath;
    void* gargs[] = { (void*)&node0, (void*)&node1, (void*)&relp, (void*)&offs,
                      (void*)&sortedp, (void*)&seeds, (void*)&vbarr, (void*)&gathp };
    hipError_t crc = hipLaunchCooperativeKernel(
        (const void*)gather_persist, dim3(1024), dim3(256), gargs, 0, stream);
    if (crc != hipSuccess) {
        for (int t = 0; t < T_STEPS; ++t)
            gather_fused<<<NGRID16 + SEED16, 256, 0, stream>>>(
                node0, node1, relp, offs, sortedp, seeds, vbarr, gathp, t);
    }

    attn_kernel<<<T_STEPS * S_SEEDS, 64, 0, stream>>>(
        (const float2*)query, gathp, seeds, (float2*)u, (unsigned*)ubf);
    score_mfma<<<1024, 256, 0, stream>>>((const unsigned short*)ubf, cb, rsum);
    final_kernel<<<T_STEPS * S_SEEDS / 4, 256, 0, stream>>>(
        (const float2*)u, ent, cidx, rsum, out);
}

// Round 6
// 1105.727 us; speedup vs baseline: 4.8124x; 4.8124x over previous
//
#include <hip/hip_runtime.h>

#define N_ENT   250002
#define DD      128
#define T_STEPS 16
#define E_EDGES 300000
#define S_SEEDS 256
#define C_NUM   50000
#define BASE    200000          // user_id_max + 1
#define NB      245             // scan blocks per step (245*1024 = 250880 >= N_ENT)
#define N_PAD   (NB * 1024)     // padded per-step offs row
#define NBKT    245             // dst buckets per step (dst >> 10), 245*1024 = N_PAD
#define BSH     10
#define CAPB    1536            // bucket capacity (mean 1229, sigma ~35 -> 8.8 sigma)
#define EPB     2048            // edges per bucketA block
#define NGRID16 ((N_ENT + 15) / 16)      // 15626 node blocks (16 nodes/block, 4/wave)
#define SEED16  (5 * S_SEEDS / 16)       // 80 seed-snapshot blocks
#define NCG     3125                     // column 16-groups (50000/16)
#define SCHUNK  49                       // colgroups per score chunk (64 chunks)

typedef __attribute__((ext_vector_type(8))) short short8;
typedef __attribute__((ext_vector_type(4))) float f32x4;

__device__ inline unsigned short f2bf(float f) {
    unsigned u = __float_as_uint(f);
    u += 0x7FFFu + ((u >> 16) & 1u);          // RNE
    return (unsigned short)(u >> 16);
}
__device__ inline float bf_lo(unsigned p) { return __uint_as_float(p << 16); }
__device__ inline float bf_hi(unsigned p) { return __uint_as_float(p & 0xffff0000u); }
__device__ inline unsigned pk2(float x, float y) {
    return (unsigned)f2bf(x) | ((unsigned)f2bf(y) << 16);
}

// ---------------- init: node_bf <- bf16(ent); zero gcount/rowsum/out ----------------
#define NODE_W (N_ENT * 64)          // 16,000,128 unsigned (2 bf16 each)
#define GC_W   (T_STEPS * NBKT)      // 3,920 bucket counters
__global__ __launch_bounds__(256) void init_kernel(
    const float2* __restrict__ ent2, unsigned* __restrict__ node_bf,
    int* __restrict__ gcount, float* __restrict__ rowsum, float* __restrict__ out)
{
    int gid = blockIdx.x * 256 + threadIdx.x;
    if (gid < NODE_W) {
        float2 v = ent2[gid];
        node_bf[gid] = pk2(v.x, v.y);
    } else if (gid < NODE_W + GC_W) {
        gcount[gid - NODE_W] = 0;
    } else if (gid < NODE_W + GC_W + T_STEPS * S_SEEDS) {
        rowsum[gid - NODE_W - GC_W] = 0.f;
    } else if (gid == NODE_W + GC_W + T_STEPS * S_SEEDS) {
        out[0] = 0.f;
    }
}

// ---------------- convert all_c to bf16 (from pristine ent) ----------------
__global__ __launch_bounds__(256) void conv_kernel(
    const float4* __restrict__ c4, ushort4* __restrict__ cb4)
{
    int gid = blockIdx.x * 256 + threadIdx.x;    // C_NUM*128/4 = 1,600,000
    float4 v = c4[gid];
    cb4[gid] = make_ushort4(f2bf(v.x), f2bf(v.y), f2bf(v.z), f2bf(v.w));
}

// ---------------- CSR build A: bucketize edges by dst>>10 (dense chunk writes) ----------------
// entry = (src | rel<<18) | (dst_low10 << 22)
__global__ __launch_bounds__(256) void bucketA(
    const int* __restrict__ esrc, const int* __restrict__ edst, const int* __restrict__ erel,
    int* __restrict__ gcount, unsigned* __restrict__ bkt)
{
    int t = blockIdx.y;
    int base = blockIdx.x * EPB;
    int tid = threadIdx.x;
    __shared__ int lcnt[NBKT];
    __shared__ int lbase[NBKT];
    for (int i = tid; i < NBKT; i += 256) lcnt[i] = 0;
    __syncthreads();
    int dl[8], sr[8], off[8], bk[8];
    #pragma unroll
    for (int i = 0; i < 8; ++i) {
        int e = base + i * 256 + tid;
        bk[i] = -1;
        if (e < E_EDGES) {
            int eb = t * E_EDGES + e;
            int dd = edst[eb];
            sr[i] = esrc[eb] | (erel[eb] << 18);
            dl[i] = dd & ((1 << BSH) - 1);
            bk[i] = dd >> BSH;
            off[i] = atomicAdd(&lcnt[bk[i]], 1);
        }
    }
    __syncthreads();
    for (int i = tid; i < NBKT; i += 256)
        lbase[i] = atomicAdd(&gcount[t * NBKT + i], lcnt[i]);
    __syncthreads();
    #pragma unroll
    for (int i = 0; i < 8; ++i) {
        if (bk[i] >= 0) {
            int pos = lbase[bk[i]] + off[i];
            if (pos < CAPB)
                bkt[((size_t)(t * NBKT + bk[i])) * CAPB + pos] =
                    (unsigned)sr[i] | ((unsigned)dl[i] << 22);
        }
    }
}

// ---------------- CSR build B1: per-bucket LDS histogram -> offs counts + block partial ----------------
__global__ __launch_bounds__(256) void histB(
    const int* __restrict__ gcount, const unsigned* __restrict__ bkt,
    int* __restrict__ offs, int* __restrict__ partials)
{
    int b = blockIdx.x, t = blockIdx.y, tid = threadIdx.x;
    __shared__ int cnt[1024];
    for (int i = tid; i < 1024; i += 256) cnt[i] = 0;
    __syncthreads();
    int n = min(gcount[t * NBKT + b], CAPB);
    const unsigned* bp = bkt + ((size_t)(t * NBKT + b)) * CAPB;
    for (int i = tid; i < n; i += 256)
        atomicAdd(&cnt[bp[i] >> 22], 1);
    __syncthreads();
    int* op = offs + (size_t)t * N_PAD + (b << BSH);
    for (int i = tid; i < 1024; i += 256) op[i] = cnt[i];
    if (tid == 0) partials[t * NB + b] = n;
}

// ---------------- CSR build 2b: exclusive scan of partials per step ----------------
__global__ __launch_bounds__(256) void scanB_kernel(int* __restrict__ partials)
{
    __shared__ int sc[256];
    int t = blockIdx.x, tid = threadIdx.x;
    int v = (tid < NB) ? partials[t * NB + tid] : 0;
    sc[tid] = v;
    __syncthreads();
    for (int off = 1; off < 256; off <<= 1) {
        int y = (tid >= off) ? sc[tid - off] : 0;
        __syncthreads();
        sc[tid] += y;
        __syncthreads();
    }
    if (tid < NB) partials[t * NB + tid] = (tid > 0) ? sc[tid - 1] : 0;
}

// ---------------- CSR build 2c: block-local exclusive scan + block prefix ----------------
__global__ __launch_bounds__(256) void scanC_kernel(
    int* __restrict__ offs, const int* __restrict__ partials)
{
    int t = blockIdx.y, b = blockIdx.x, tid = threadIdx.x;
    int* base = offs + (size_t)t * N_PAD + b * 1024 + tid * 4;
    int4 v = *(const int4*)base;
    int s = v.x + v.y + v.z + v.w;
    int lane = tid & 63, wv = tid >> 6;
    int x = s;                               // inclusive wave scan
    #pragma unroll
    for (int off = 1; off < 64; off <<= 1) {
        int y = __shfl_up(x, off, 64);
        if (lane >= off) x += y;
    }
    __shared__ int wsum[4];
    if (lane == 63) wsum[wv] = x;
    __syncthreads();
    int prefix = partials[t * NB + b];
    for (int w = 0; w < 4; ++w) prefix += (w < wv) ? wsum[w] : 0;
    int excl = prefix + x - s;               // exclusive of this thread's 4 elems
    int4 o;
    o.x = excl; o.y = o.x + v.x; o.z = o.y + v.y; o.w = o.z + v.z;
    *(int4*)base = o;
}

// ---------------- CSR build B2: per-bucket scatter into L2-local CSR window ----------------
// offs stays START offsets; sortedp entries are packed src|rel<<18 (4 B)
__global__ __launch_bounds__(256) void scatB(
    const int* __restrict__ gcount, const unsigned* __restrict__ bkt,
    const int* __restrict__ offs, unsigned* __restrict__ sortedp)
{
    int b = blockIdx.x, t = blockIdx.y, tid = threadIdx.x;
    __shared__ int cur[1024];
    const int* op = offs + (size_t)t * N_PAD + (b << BSH);
    for (int i = tid; i < 1024; i += 256) cur[i] = op[i];
    __syncthreads();
    int n = min(gcount[t * NBKT + b], CAPB);
    const unsigned* bp = bkt + ((size_t)(t * NBKT + b)) * CAPB;
    unsigned* sp = sortedp + (size_t)t * E_EDGES;
    for (int i = tid; i < n; i += 256) {
        unsigned e = bp[i];
        int pos = atomicAdd(&cur[e >> 22], 1);
        sp[pos] = e & 0x3FFFFFu;
    }
}

// ---------------- per-step: fused mean-message + residual update (ping-pong) ----------------
// 4 nodes per wave (16 lanes each, uint4 = 16B/lane) -> 4 independent memory chains/wave.
// blocks [0, NGRID16): update node_new.  blocks [NGRID16, +SEED16): recompute seed nodes
// (bit-identical path) and write fp32 snapshots to gath.
__global__ __launch_bounds__(256) void gather_fused(
    const unsigned* __restrict__ node_old, unsigned* __restrict__ node_new,
    const float2* __restrict__ rel2, const int* __restrict__ offs,
    const unsigned* __restrict__ sortedp, const int* __restrict__ seeds,
    float2* __restrict__ gath2, int t)
{
    int wv = threadIdx.x >> 6;
    int lane = threadIdx.x & 63;
    int grp = lane >> 4;          // 4 nodes per wave
    int l16 = lane & 15;          // 16 lanes per node, 16 B each
    int bx = blockIdx.x;
    int n = 0, gslot = -1;
    bool active;
    if (bx < NGRID16) {
        n = bx * 16 + wv * 4 + grp;
        active = (n < N_ENT);
    } else {
        int g = (bx - NGRID16) * 16 + wv * 4 + grp;   // 0..1279
        int j = g >> 8;
        active = (t + j < T_STEPS);
        if (active) {
            n = seeds[t * S_SEEDS + g];               // == seeds[(t+j)*256 + (g&255)]
            gslot = (((t + j) * 5 + (4 - j)) * S_SEEDS + (g & 255)) * 64 + l16 * 4;
        }
    }
    if (active) {
        const int* op = offs + (size_t)t * N_PAD;
        int start = op[n];
        int end = op[n + 1];
        uint4 nb = *((const uint4*)(node_old + (size_t)n * 64) + l16);
        float vx0 = bf_lo(nb.x), vy0 = bf_hi(nb.x);
        float vx1 = bf_lo(nb.y), vy1 = bf_hi(nb.y);
        float vx2 = bf_lo(nb.z), vy2 = bf_hi(nb.z);
        float vx3 = bf_lo(nb.w), vy3 = bf_hi(nb.w);
        if (end > start) {
            const unsigned* sp = sortedp + (size_t)t * E_EDGES;
            float ax0=0.f,ay0=0.f,ax1=0.f,ay1=0.f,ax2=0.f,ay2=0.f,ax3=0.f,ay3=0.f;
            for (int p = start; p < end; ++p) {
                unsigned pr = sp[p];
                uint4 sb = *((const uint4*)(node_old + (size_t)(pr & 0x3FFFFu) * 64) + l16);
                const float* rp = (const float*)(rel2 + (pr >> 18) * 64) + l16 * 8;
                float4 r01 = *(const float4*)rp;
                float4 r23 = *(const float4*)(rp + 4);
                ax0 += bf_lo(sb.x) * r01.x; ay0 += bf_hi(sb.x) * r01.y;
                ax1 += bf_lo(sb.y) * r01.z; ay1 += bf_hi(sb.y) * r01.w;
                ax2 += bf_lo(sb.z) * r23.x; ay2 += bf_hi(sb.z) * r23.y;
                ax3 += bf_lo(sb.w) * r23.z; ay3 += bf_hi(sb.w) * r23.w;
            }
            float inv = 1.0f / (float)(end - start);
            vx0 += ax0 * inv; vy0 += ay0 * inv;
            vx1 += ax1 * inv; vy1 += ay1 * inv;
            vx2 += ax2 * inv; vy2 += ay2 * inv;
            vx3 += ax3 * inv; vy3 += ay3 * inv;
        }
        uint4 o;
        o.x = pk2(vx0, vy0); o.y = pk2(vx1, vy1);
        o.z = pk2(vx2, vy2); o.w = pk2(vx3, vy3);
        if (gslot >= 0) {
            gath2[gslot + 0] = make_float2(bf_lo(o.x), bf_hi(o.x));
            gath2[gslot + 1] = make_float2(bf_lo(o.y), bf_hi(o.y));
            gath2[gslot + 2] = make_float2(bf_lo(o.z), bf_hi(o.z));
            gath2[gslot + 3] = make_float2(bf_lo(o.w), bf_hi(o.w));
        } else {
            *((uint4*)(node_new + (size_t)n * 64) + l16) = o;
        }
    }
}

// ---------------- 5-snapshot attention per (t,s): one wave each; writes u fp32 + bf16 ----------------
__global__ __launch_bounds__(64) void attn_kernel(
    const float2* __restrict__ q2, const float2* __restrict__ g2,
    const int* __restrict__ seeds, float2* __restrict__ u2, unsigned* __restrict__ ubf)
{
    int b = blockIdx.x;          // 4096 = T*S
    int t = b >> 8;
    int s = b & 255;
    int lane = threadIdx.x;
    int seed = seeds[t * S_SEEDS + s];
    float2 q = q2[seed * 64 + lane];
    float2 g[5];
    float att[5];
    #pragma unroll
    for (int w = 0; w < 5; ++w) {
        float2 gv = g2[((t * 5 + w) * S_SEEDS + s) * 64 + lane];
        g[w] = gv;
        float p = gv.x * q.x + gv.y * q.y;
        #pragma unroll
        for (int off = 32; off > 0; off >>= 1) p += __shfl_xor(p, off, 64);
        att[w] = (w >= 4 - t) ? p : -1e9f;   // invalid slots masked -> weight exactly 0
    }
    float m = -1e30f;
    #pragma unroll
    for (int w = 0; w < 5; ++w) m = fmaxf(m, att[w]);
    float den = 0.f;
    #pragma unroll
    for (int w = 0; w < 5; ++w) den += __expf(att[w] - m);
    float invd = 1.0f / den;
    float2 o = make_float2(0.f, 0.f);
    #pragma unroll
    for (int w = 0; w < 5; ++w) {
        float wt = __expf(att[w] - m) * invd;
        o.x += wt * g[w].x;
        o.y += wt * g[w].y;
    }
    int idx = (t * S_SEEDS + s) * 64 + lane;
    u2[idx] = o;
    ubf[idx] = pk2(o.x, o.y);
}

// ---------------- transposed-accumulate MFMA score GEMM + streaming sum(exp) ----------------
// A-operand = cb columns (M dim), B-operand = ub rows (N dim = lane&15, FIXED per lane).
// Lane accumulates sum_r expf(d[r]) privately -> no cross-lane/LDS in the loop.
// Wave holds 4 row-sets (64 rows); block = 4 waves = 256 rows; 16 row-blocks x 64 chunks.
// XCD swizzle: all 16 row-blocks of a chunk land on one XCD -> chunk (200 KB) L2-resident.
__global__ __launch_bounds__(256) void score_mfma(
    const unsigned short* __restrict__ ub, const unsigned short* __restrict__ cb,
    float* __restrict__ rowsum)
{
    int tid = threadIdx.x;
    int wv = tid >> 6, lane = tid & 63;
    int col16 = lane & 15, quad = lane >> 4;
    int b = blockIdx.x;                 // 0..1023
    int xcd = b & 7, k = b >> 3;
    int ychunk = xcd + 8 * (k >> 4);    // 0..63, ychunk%8 == xcd
    int xblk = k & 15;                  // 0..15
    int rbase = xblk * 256 + wv * 64;

    short8 B[4][4];                     // 4 row-sets x 4 K-slices (ub register-resident)
    #pragma unroll
    for (int s = 0; s < 4; ++s) {
        const unsigned short* bp = ub + (size_t)(rbase + s * 16 + col16) * DD + quad * 8;
        #pragma unroll
        for (int kk = 0; kk < 4; ++kk) B[s][kk] = *(const short8*)(bp + kk * 32);
    }

    float acc0 = 0.f, acc1 = 0.f, acc2 = 0.f, acc3 = 0.f;
    int c0 = ychunk * SCHUNK;
    int c1 = min(c0 + SCHUNK, NCG);
    const unsigned short* abase = cb + col16 * DD + quad * 8;   // + c*2048

#define SCORE_STEP(AF)  do {                                                              \
        f32x4 d0 = {0.f,0.f,0.f,0.f}, d1 = {0.f,0.f,0.f,0.f};                             \
        f32x4 d2 = {0.f,0.f,0.f,0.f}, d3 = {0.f,0.f,0.f,0.f};                             \
        _Pragma("unroll")                                                                 \
        for (int kk = 0; kk < 4; ++kk) {                                                  \
            d0 = __builtin_amdgcn_mfma_f32_16x16x32_bf16(AF[kk], B[0][kk], d0, 0, 0, 0);  \
            d1 = __builtin_amdgcn_mfma_f32_16x16x32_bf16(AF[kk], B[1][kk], d1, 0, 0, 0);  \
            d2 = __builtin_amdgcn_mfma_f32_16x16x32_bf16(AF[kk], B[2][kk], d2, 0, 0, 0);  \
            d3 = __builtin_amdgcn_mfma_f32_16x16x32_bf16(AF[kk], B[3][kk], d3, 0, 0, 0);  \
        }                                                                                 \
        _Pragma("unroll")                                                                 \
        for (int r = 0; r < 4; ++r) {                                                     \
            acc0 += __expf(d0[r]); acc1 += __expf(d1[r]);                                 \
            acc2 += __expf(d2[r]); acc3 += __expf(d3[r]);                                 \
        } } while (0)

    short8 A0[4], A1[4];
    #pragma unroll
    for (int kk = 0; kk < 4; ++kk)
        A0[kk] = *(const short8*)(abase + (size_t)c0 * 2048 + kk * 32);
    int c = c0;
    for (; c + 2 <= c1; c += 2) {
        #pragma unroll
        for (int kk = 0; kk < 4; ++kk)
            A1[kk] = *(const short8*)(abase + (size_t)(c + 1) * 2048 + kk * 32);
        SCORE_STEP(A0);
        if (c + 2 < c1) {
            #pragma unroll
            for (int kk = 0; kk < 4; ++kk)
                A0[kk] = *(const short8*)(abase + (size_t)(c + 2) * 2048 + kk * 32);
        }
        SCORE_STEP(A1);
    }
    if (c < c1) SCORE_STEP(A0);

    acc0 += __shfl_xor(acc0, 16, 64); acc0 += __shfl_xor(acc0, 32, 64);
    acc1 += __shfl_xor(acc1, 16, 64); acc1 += __shfl_xor(acc1, 32, 64);
    acc2 += __shfl_xor(acc2, 16, 64); acc2 += __shfl_xor(acc2, 32, 64);
    acc3 += __shfl_xor(acc3, 16, 64); acc3 += __shfl_xor(acc3, 32, 64);
    if (quad == 0) {
        atomicAdd(&rowsum[rbase +  0 + col16], acc0);
        atomicAdd(&rowsum[rbase + 16 + col16], acc1);
        atomicAdd(&rowsum[rbase + 32 + col16], acc2);
        atomicAdd(&rowsum[rbase + 48 + col16], acc3);
    }
}

// ---------------- final: loss = sum(log(rowsum) - pos), pos in fp32 ----------------
__global__ __launch_bounds__(256) void final_kernel(
    const float2* __restrict__ u2, const float* __restrict__ ent,
    const int* __restrict__ cidx, const float* __restrict__ rowsum,
    float* __restrict__ out)
{
    int wv = threadIdx.x >> 6, lane = threadIdx.x & 63;
    int row = blockIdx.x * 4 + wv;       // grid 1024 -> 4096 rows
    int ci = cidx[row];
    const float2* tp = (const float2*)(ent + (size_t)(BASE + ci) * DD);
    float2 a = u2[row * 64 + lane];
    float2 t = tp[lane];
    float p = a.x * t.x + a.y * t.y;
    #pragma unroll
    for (int off = 32; off > 0; off >>= 1) p += __shfl_xor(p, off, 64);
    if (lane == 0) atomicAdd(out, logf(rowsum[row]) - p);
}

extern "C" void kernel_launch(void* const* d_in, const int* in_sizes, int n_in,
                              void* d_out, int out_size, void* d_ws, size_t ws_size,
                              hipStream_t stream)
{
    (void)in_sizes; (void)n_in; (void)out_size; (void)ws_size;
    const float* ent   = (const float*)d_in[0];
    const float* query = (const float*)d_in[1];
    const float* rel   = (const float*)d_in[2];
    const int* esrc    = (const int*)d_in[3];
    const int* edst    = (const int*)d_in[4];
    const int* erel    = (const int*)d_in[5];
    const int* seeds   = (const int*)d_in[6];
    const int* cidx    = (const int*)d_in[7];
    float* out = (float*)d_out;

    // ws layout: nodeA | nodeB | offs | partials | gcount | bkt | sortedp | gath | u | ubf | cb | rowsum
    char* ws = (char*)d_ws;
    size_t off = 0;
    unsigned* nodeA   = (unsigned*)(ws + off);       off += (size_t)N_ENT * DD * 2;            // 64.0 MB
    unsigned* nodeB   = (unsigned*)(ws + off);       off += (size_t)N_ENT * DD * 2;            // 64.0 MB
    int*      offs    = (int*)(ws + off);            off += (size_t)T_STEPS * N_PAD * 4;       // 16.1 MB
    int*      partials= (int*)(ws + off);            off += (size_t)T_STEPS * NB * 4;          // 15.7 KB
    int*      gcount  = (int*)(ws + off);            off += (size_t)T_STEPS * NBKT * 4;        // 15.7 KB
    unsigned* bkt     = (unsigned*)(ws + off);       off += (size_t)T_STEPS * NBKT * CAPB * 4; // 24.1 MB
    unsigned* sortedp = (unsigned*)(ws + off);       off += (size_t)T_STEPS * E_EDGES * 4;     // 19.2 MB
    float*    gath    = (float*)(ws + off);          off += (size_t)T_STEPS * 5 * S_SEEDS * DD * 4;
    float*    u       = (float*)(ws + off);          off += (size_t)T_STEPS * S_SEEDS * DD * 4;
    unsigned* ubf     = (unsigned*)(ws + off);       off += (size_t)T_STEPS * S_SEEDS * DD * 2;
    unsigned short* cb = (unsigned short*)(ws + off); off += (size_t)C_NUM * DD * 2;
    float*    rsum    = (float*)(ws + off);          off += (size_t)T_STEPS * S_SEEDS * 4;

    int init_items = NODE_W + GC_W + T_STEPS * S_SEEDS + 1;
    init_kernel<<<(init_items + 255) / 256, 256, 0, stream>>>(
        (const float2*)ent, nodeA, gcount, rsum, out);
    conv_kernel<<<C_NUM * DD / 4 / 256, 256, 0, stream>>>(
        (const float4*)(ent + (size_t)BASE * DD), (ushort4*)cb);

    dim3 bgrid((E_EDGES + EPB - 1) / EPB, T_STEPS);   // (147, 16)
    dim3 kgrid(NBKT, T_STEPS);                        // (245, 16)
    bucketA<<<bgrid, 256, 0, stream>>>(esrc, edst, erel, gcount, bkt);
    histB<<<kgrid, 256, 0, stream>>>(gcount, bkt, offs, partials);
    scanB_kernel<<<T_STEPS, 256, 0, stream>>>(partials);
    scanC_kernel<<<kgrid, 256, 0, stream>>>(offs, partials);
    scatB<<<kgrid, 256, 0, stream>>>(gcount, bkt, offs, sortedp);

    unsigned* cur = nodeA;
    unsigned* nxt = nodeB;
    for (int t = 0; t < T_STEPS; ++t) {
        gather_fused<<<NGRID16 + SEED16, 256, 0, stream>>>(
            cur, nxt, (const float2*)rel, offs, sortedp, seeds, (float2*)gath, t);
        unsigned* tmp = cur; cur = nxt; nxt = tmp;
    }
    attn_kernel<<<T_STEPS * S_SEEDS, 64, 0, stream>>>(
        (const float2*)query, (const float2*)gath, seeds, (float2*)u, (unsigned*)ubf);
    score_mfma<<<1024, 256, 0, stream>>>((const unsigned short*)ubf, cb, rsum);
    final_kernel<<<T_STEPS * S_SEEDS / 4, 256, 0, stream>>>(
        (const float2*)u, ent, cidx, rsum, out);
}

// Round 7
// 1105.600 us; speedup vs baseline: 4.8130x; 1.0001x over previous
//
#include <hip/hip_runtime.h>

#define N_ENT   250002
#define DD      128
#define T_STEPS 16
#define E_EDGES 300000
#define S_SEEDS 256
#define C_NUM   50000
#define BASE    200000          // user_id_max + 1
#define NB      245             // scan blocks per step (245*1024 = 250880 >= N_ENT)
#define N_PAD   (NB * 1024)     // padded per-step offs row
#define NBKT    245             // dst buckets per step (dst >> 10), 245*1024 = N_PAD
#define BSH     10
#define CAPB    1536            // bucket capacity (mean 1229, sigma ~35 -> 8.8 sigma)
#define EPB     2048            // edges per bucketA block
#define NGRID16 ((N_ENT + 15) / 16)      // 15626 node blocks (16 nodes/block, 4/wave)
#define SEED16  (5 * S_SEEDS / 16)       // 80 seed-snapshot blocks
#define NCG     3125                     // column 16-groups (50000/16)
#define SCHUNK  25                       // colgroups per score chunk (128 chunks)
#define OMSK    0x7FFFFFFF               // offs value mask (bit31 = version bit)
#define LOG2E   1.44269504088896340736f

typedef __attribute__((ext_vector_type(8))) short short8;
typedef __attribute__((ext_vector_type(4))) float f32x4;

__device__ inline unsigned short f2bf(float f) {
    unsigned u = __float_as_uint(f);
    u += 0x7FFFu + ((u >> 16) & 1u);          // RNE
    return (unsigned short)(u >> 16);
}
__device__ inline float bf_lo(unsigned p) { return __uint_as_float(p << 16); }
__device__ inline float bf_hi(unsigned p) { return __uint_as_float(p & 0xffff0000u); }
__device__ inline unsigned pk2(float x, float y) {
    return (unsigned)f2bf(x) | ((unsigned)f2bf(y) << 16);
}

// ---------------- init: node_bf <- bf16(ent); zero gcount/rowsum/out ----------------
#define NODE_W (N_ENT * 64)          // 16,000,128 unsigned (2 bf16 each)
#define GC_W   (T_STEPS * NBKT)      // 3,920 bucket counters
__global__ __launch_bounds__(256) void init_kernel(
    const float2* __restrict__ ent2, unsigned* __restrict__ node_bf,
    int* __restrict__ gcount, float* __restrict__ rowsum, float* __restrict__ out)
{
    int gid = blockIdx.x * 256 + threadIdx.x;
    if (gid < NODE_W) {
        float2 v = ent2[gid];
        node_bf[gid] = pk2(v.x, v.y);
    } else if (gid < NODE_W + GC_W) {
        gcount[gid - NODE_W] = 0;
    } else if (gid < NODE_W + GC_W + T_STEPS * S_SEEDS) {
        rowsum[gid - NODE_W - GC_W] = 0.f;
    } else if (gid == NODE_W + GC_W + T_STEPS * S_SEEDS) {
        out[0] = 0.f;
    }
}

// ---------------- convert all_c to bf16, pre-scaled by log2(e) (score path only) ------
// rowsum = sum_c exp(u.c) = sum_c exp2((u*log2e).c) -> score loop uses native v_exp_f32
__global__ __launch_bounds__(256) void conv_kernel(
    const float4* __restrict__ c4, ushort4* __restrict__ cb4)
{
    int gid = blockIdx.x * 256 + threadIdx.x;    // C_NUM*128/4 = 1,600,000
    float4 v = c4[gid];
    cb4[gid] = make_ushort4(f2bf(v.x * LOG2E), f2bf(v.y * LOG2E),
                            f2bf(v.z * LOG2E), f2bf(v.w * LOG2E));
}

// ---------------- CSR build A: bucketize edges by dst>>10 (dense chunk writes) ----------------
// entry = (src | rel<<18) | (dst_low10 << 22)
__global__ __launch_bounds__(256) void bucketA(
    const int* __restrict__ esrc, const int* __restrict__ edst, const int* __restrict__ erel,
    int* __restrict__ gcount, unsigned* __restrict__ bkt)
{
    int t = blockIdx.y;
    int base = blockIdx.x * EPB;
    int tid = threadIdx.x;
    __shared__ int lcnt[NBKT];
    __shared__ int lbase[NBKT];
    for (int i = tid; i < NBKT; i += 256) lcnt[i] = 0;
    __syncthreads();
    int dl[8], sr[8], off[8], bk[8];
    #pragma unroll
    for (int i = 0; i < 8; ++i) {
        int e = base + i * 256 + tid;
        bk[i] = -1;
        if (e < E_EDGES) {
            int eb = t * E_EDGES + e;
            int dd = edst[eb];
            sr[i] = esrc[eb] | (erel[eb] << 18);
            dl[i] = dd & ((1 << BSH) - 1);
            bk[i] = dd >> BSH;
            off[i] = atomicAdd(&lcnt[bk[i]], 1);
        }
    }
    __syncthreads();
    for (int i = tid; i < NBKT; i += 256)
        lbase[i] = atomicAdd(&gcount[t * NBKT + i], lcnt[i]);
    __syncthreads();
    #pragma unroll
    for (int i = 0; i < 8; ++i) {
        if (bk[i] >= 0) {
            int pos = lbase[bk[i]] + off[i];
            if (pos < CAPB)
                bkt[((size_t)(t * NBKT + bk[i])) * CAPB + pos] =
                    (unsigned)sr[i] | ((unsigned)dl[i] << 22);
        }
    }
}

// ---------------- CSR build B1: per-bucket LDS histogram -> offs counts + block partial ----------------
__global__ __launch_bounds__(256) void histB(
    const int* __restrict__ gcount, const unsigned* __restrict__ bkt,
    int* __restrict__ offs, int* __restrict__ partials)
{
    int b = blockIdx.x, t = blockIdx.y, tid = threadIdx.x;
    __shared__ int cnt[1024];
    for (int i = tid; i < 1024; i += 256) cnt[i] = 0;
    __syncthreads();
    int n = min(gcount[t * NBKT + b], CAPB);
    const unsigned* bp = bkt + ((size_t)(t * NBKT + b)) * CAPB;
    for (int i = tid; i < n; i += 256)
        atomicAdd(&cnt[bp[i] >> 22], 1);
    __syncthreads();
    int* op = offs + (size_t)t * N_PAD + (b << BSH);
    for (int i = tid; i < 1024; i += 256) op[i] = cnt[i];
    if (tid == 0) partials[t * NB + b] = n;
}

// ---------------- version-bit build: vb[t][n] = buffer holding n's value at START of step t ----
// runs after histB (offs holds per-step degree counts), before scanC (which embeds vb into offs)
__global__ __launch_bounds__(256) void vb_build(
    const int* __restrict__ offs, unsigned char* __restrict__ vbarr)
{
    int n = blockIdx.x * 256 + threadIdx.x;
    if (n >= N_ENT) return;
    int v = 0;
    #pragma unroll
    for (int t = 0; t < T_STEPS; ++t) {
        vbarr[(size_t)t * N_PAD + n] = (unsigned char)v;
        v ^= (offs[(size_t)t * N_PAD + n] > 0) ? 1 : 0;
    }
}

// ---------------- CSR build 2b: exclusive scan of partials per step ----------------
__global__ __launch_bounds__(256) void scanB_kernel(int* __restrict__ partials)
{
    __shared__ int sc[256];
    int t = blockIdx.x, tid = threadIdx.x;
    int v = (tid < NB) ? partials[t * NB + tid] : 0;
    sc[tid] = v;
    __syncthreads();
    for (int off = 1; off < 256; off <<= 1) {
        int y = (tid >= off) ? sc[tid - off] : 0;
        __syncthreads();
        sc[tid] += y;
        __syncthreads();
    }
    if (tid < NB) partials[t * NB + tid] = (tid > 0) ? sc[tid - 1] : 0;
}

// ---------------- CSR build 2c: block-local exclusive scan + block prefix + vb bit31 ----------
__global__ __launch_bounds__(256) void scanC_kernel(
    int* __restrict__ offs, const int* __restrict__ partials,
    const unsigned char* __restrict__ vbarr)
{
    int t = blockIdx.y, b = blockIdx.x, tid = threadIdx.x;
    int* base = offs + (size_t)t * N_PAD + b * 1024 + tid * 4;
    int4 v = *(const int4*)base;
    int s = v.x + v.y + v.z + v.w;
    int lane = tid & 63, wv = tid >> 6;
    int x = s;                               // inclusive wave scan
    #pragma unroll
    for (int off = 1; off < 64; off <<= 1) {
        int y = __shfl_up(x, off, 64);
        if (lane >= off) x += y;
    }
    __shared__ int wsum[4];
    if (lane == 63) wsum[wv] = x;
    __syncthreads();
    int prefix = partials[t * NB + b];
    for (int w = 0; w < 4; ++w) prefix += (w < wv) ? wsum[w] : 0;
    int excl = prefix + x - s;               // exclusive of this thread's 4 elems
    int4 o;
    o.x = excl; o.y = o.x + v.x; o.z = o.y + v.y; o.w = o.z + v.z;
    // embed version bit (bit 31); readers mask with OMSK
    uchar4 vb4 = *(const uchar4*)(vbarr + (size_t)t * N_PAD + b * 1024 + tid * 4);
    o.x |= ((int)vb4.x) << 31;
    o.y |= ((int)vb4.y) << 31;
    o.z |= ((int)vb4.z) << 31;
    o.w |= ((int)vb4.w) << 31;
    *(int4*)base = o;
}

// ---------------- CSR build B2: per-bucket scatter into L2-local CSR window ----------------
// sortedp entry: src | rel<<18 | vb(src,t)<<22
__global__ __launch_bounds__(256) void scatB(
    const int* __restrict__ gcount, const unsigned* __restrict__ bkt,
    const int* __restrict__ offs, const unsigned char* __restrict__ vbarr,
    unsigned* __restrict__ sortedp)
{
    int b = blockIdx.x, t = blockIdx.y, tid = threadIdx.x;
    __shared__ int cur[1024];
    const int* op = offs + (size_t)t * N_PAD + (b << BSH);
    for (int i = tid; i < 1024; i += 256) cur[i] = op[i] & OMSK;
    __syncthreads();
    int n = min(gcount[t * NBKT + b], CAPB);
    const unsigned* bp = bkt + ((size_t)(t * NBKT + b)) * CAPB;
    unsigned* sp = sortedp + (size_t)t * E_EDGES;
    const unsigned char* vbt = vbarr + (size_t)t * N_PAD;
    for (int i = tid; i < n; i += 256) {
        unsigned e = bp[i];
        int pos = atomicAdd(&cur[e >> 22], 1);
        unsigned src = e & 0x3FFFFu;
        sp[pos] = (e & 0x3FFFFFu) | ((unsigned)vbt[src] << 22);
    }
}

// ---------------- per-step: fused mean-message + residual update (vb ping-pong) ----------
// 4 nodes per wave (16 lanes each, uint4 = 16B/lane). vb rides in offs bit31 (no extra
// load/chain hop). deg==0 main-path nodes do NOTHING (30% of rows skip both streams).
// blocks [NGRID16, +SEED16): recompute seed nodes (bit-identical) -> fp32 snapshots to gath.
__global__ __launch_bounds__(256) void gather_fused(
    const unsigned* __restrict__ node0, unsigned* __restrict__ node1,
    const float2* __restrict__ rel2, const int* __restrict__ offs,
    const unsigned* __restrict__ sortedp, const int* __restrict__ seeds,
    float2* __restrict__ gath2, int t)
{
    int wv = threadIdx.x >> 6;
    int lane = threadIdx.x & 63;
    int grp = lane >> 4;          // 4 nodes per wave
    int l16 = lane & 15;          // 16 lanes per node, 16 B each
    int bx = blockIdx.x;
    int n = 0, gslot = -1;
    bool active;
    if (bx < NGRID16) {
        n = bx * 16 + wv * 4 + grp;
        active = (n < N_ENT);
    } else {
        int g = (bx - NGRID16) * 16 + wv * 4 + grp;   // 0..1279
        int j = g >> 8;
        active = (t + j < T_STEPS);
        if (active) {
            n = seeds[t * S_SEEDS + g];               // == seeds[(t+j)*256 + (g&255)]
            gslot = (((t + j) * 5 + (4 - j)) * S_SEEDS + (g & 255)) * 64 + l16 * 4;
        }
    }
    if (active) {
        const int* op = offs + (size_t)t * N_PAD;
        int sraw = op[n];
        int eraw = op[n + 1];
        int start = sraw & OMSK;
        int end = eraw & OMSK;
        if (end == start && gslot < 0) return;       // untouched node: nothing to do
        unsigned vb = (unsigned)sraw >> 31;
        const unsigned* selfb = vb ? node1 : node0;
        uint4 nb = *((const uint4*)(selfb + (size_t)n * 64) + l16);
        float vx0 = bf_lo(nb.x), vy0 = bf_hi(nb.x);
        float vx1 = bf_lo(nb.y), vy1 = bf_hi(nb.y);
        float vx2 = bf_lo(nb.z), vy2 = bf_hi(nb.z);
        float vx3 = bf_lo(nb.w), vy3 = bf_hi(nb.w);
        if (end > start) {
            const unsigned* sp = sortedp + (size_t)t * E_EDGES;
            float ax0=0.f,ay0=0.f,ax1=0.f,ay1=0.f,ax2=0.f,ay2=0.f,ax3=0.f,ay3=0.f;
            for (int p = start; p < end; ++p) {
                unsigned pr = sp[p];
                const unsigned* gb = (pr & (1u << 22)) ? node1 : node0;
                uint4 sb = *((const uint4*)(gb + (size_t)(pr & 0x3FFFFu) * 64) + l16);
                const float* rp = (const float*)(rel2 + ((pr >> 18) & 15u) * 64) + l16 * 8;
                float4 r01 = *(const float4*)rp;
                float4 r23 = *(const float4*)(rp + 4);
                ax0 += bf_lo(sb.x) * r01.x; ay0 += bf_hi(sb.x) * r01.y;
                ax1 += bf_lo(sb.y) * r01.z; ay1 += bf_hi(sb.y) * r01.w;
                ax2 += bf_lo(sb.z) * r23.x; ay2 += bf_hi(sb.z) * r23.y;
                ax3 += bf_lo(sb.w) * r23.z; ay3 += bf_hi(sb.w) * r23.w;
            }
            float inv = 1.0f / (float)(end - start);
            vx0 += ax0 * inv; vy0 += ay0 * inv;
            vx1 += ax1 * inv; vy1 += ay1 * inv;
            vx2 += ax2 * inv; vy2 += ay2 * inv;
            vx3 += ax3 * inv; vy3 += ay3 * inv;
        }
        uint4 o;
        o.x = pk2(vx0, vy0); o.y = pk2(vx1, vy1);
        o.z = pk2(vx2, vy2); o.w = pk2(vx3, vy3);
        if (gslot >= 0) {
            gath2[gslot + 0] = make_float2(bf_lo(o.x), bf_hi(o.x));
            gath2[gslot + 1] = make_float2(bf_lo(o.y), bf_hi(o.y));
            gath2[gslot + 2] = make_float2(bf_lo(o.z), bf_hi(o.z));
            gath2[gslot + 3] = make_float2(bf_lo(o.w), bf_hi(o.w));
        } else {
            unsigned* outb = vb ? (unsigned*)node0 : node1;
            *((uint4*)(outb + (size_t)n * 64) + l16) = o;
        }
    }
}

// ---------------- 5-snapshot attention per (t,s): one wave each; writes u fp32 + bf16 ----------------
__global__ __launch_bounds__(64) void attn_kernel(
    const float2* __restrict__ q2, const float2* __restrict__ g2,
    const int* __restrict__ seeds, float2* __restrict__ u2, unsigned* __restrict__ ubf)
{
    int b = blockIdx.x;          // 4096 = T*S
    int t = b >> 8;
    int s = b & 255;
    int lane = threadIdx.x;
    int seed = seeds[t * S_SEEDS + s];
    float2 q = q2[seed * 64 + lane];
    float2 g[5];
    float att[5];
    #pragma unroll
    for (int w = 0; w < 5; ++w) {
        float2 gv = g2[((t * 5 + w) * S_SEEDS + s) * 64 + lane];
        g[w] = gv;
        float p = gv.x * q.x + gv.y * q.y;
        #pragma unroll
        for (int off = 32; off > 0; off >>= 1) p += __shfl_xor(p, off, 64);
        att[w] = (w >= 4 - t) ? p : -1e9f;   // invalid slots masked -> weight exactly 0
    }
    float m = -1e30f;
    #pragma unroll
    for (int w = 0; w < 5; ++w) m = fmaxf(m, att[w]);
    float den = 0.f;
    #pragma unroll
    for (int w = 0; w < 5; ++w) den += __expf(att[w] - m);
    float invd = 1.0f / den;
    float2 o = make_float2(0.f, 0.f);
    #pragma unroll
    for (int w = 0; w < 5; ++w) {
        float wt = __expf(att[w] - m) * invd;
        o.x += wt * g[w].x;
        o.y += wt * g[w].y;
    }
    int idx = (t * S_SEEDS + s) * 64 + lane;
    u2[idx] = o;
    ubf[idx] = pk2(o.x, o.y);
}

// ---------------- transposed-accumulate MFMA score GEMM + streaming sum(exp2) ----------------
// A-operand = cb columns (pre-scaled by log2e), B-operand = ub rows (lane&15, fixed/lane).
// Lane-private acc += exp2(d[r]) -> no cross-lane/LDS in loop; native v_exp_f32.
// 128 chunks x 16 row-blocks = 2048 blocks (8/CU issued, ~6 co-resident at VGPR~76).
__global__ __launch_bounds__(256) void score_mfma(
    const unsigned short* __restrict__ ub, const unsigned short* __restrict__ cb,
    float* __restrict__ rowsum)
{
    int tid = threadIdx.x;
    int wv = tid >> 6, lane = tid & 63;
    int col16 = lane & 15, quad = lane >> 4;
    int b = blockIdx.x;                 // 0..2047
    int xcd = b & 7, k = b >> 3;        // k: 0..255
    int ychunk = xcd + 8 * (k >> 4);    // 0..127, ychunk%8 == xcd (chunk L2-local per XCD)
    int xblk = k & 15;                  // 0..15
    int rbase = xblk * 256 + wv * 64;

    short8 B[4][4];                     // 4 row-sets x 4 K-slices (ub register-resident)
    #pragma unroll
    for (int s = 0; s < 4; ++s) {
        const unsigned short* bp = ub + (size_t)(rbase + s * 16 + col16) * DD + quad * 8;
        #pragma unroll
        for (int kk = 0; kk < 4; ++kk) B[s][kk] = *(const short8*)(bp + kk * 32);
    }

    float acc0 = 0.f, acc1 = 0.f, acc2 = 0.f, acc3 = 0.f;
    int c0 = ychunk * SCHUNK;
    int c1 = min(c0 + SCHUNK, NCG);
    const unsigned short* abase = cb + col16 * DD + quad * 8;   // + c*2048

#define SCORE_STEP(AF)  do {                                                              \
        f32x4 d0 = {0.f,0.f,0.f,0.f}, d1 = {0.f,0.f,0.f,0.f};                             \
        f32x4 d2 = {0.f,0.f,0.f,0.f}, d3 = {0.f,0.f,0.f,0.f};                             \
        _Pragma("unroll")                                                                 \
        for (int kk = 0; kk < 4; ++kk) {                                                  \
            d0 = __builtin_amdgcn_mfma_f32_16x16x32_bf16(AF[kk], B[0][kk], d0, 0, 0, 0);  \
            d1 = __builtin_amdgcn_mfma_f32_16x16x32_bf16(AF[kk], B[1][kk], d1, 0, 0, 0);  \
            d2 = __builtin_amdgcn_mfma_f32_16x16x32_bf16(AF[kk], B[2][kk], d2, 0, 0, 0);  \
            d3 = __builtin_amdgcn_mfma_f32_16x16x32_bf16(AF[kk], B[3][kk], d3, 0, 0, 0);  \
        }                                                                                 \
        _Pragma("unroll")                                                                 \
        for (int r = 0; r < 4; ++r) {                                                     \
            acc0 += exp2f(d0[r]); acc1 += exp2f(d1[r]);                                   \
            acc2 += exp2f(d2[r]); acc3 += exp2f(d3[r]);                                   \
        } } while (0)

    if (c0 < c1) {
        short8 A0[4], A1[4];
        #pragma unroll
        for (int kk = 0; kk < 4; ++kk)
            A0[kk] = *(const short8*)(abase + (size_t)c0 * 2048 + kk * 32);
        int c = c0;
        for (; c + 2 <= c1; c += 2) {
            #pragma unroll
            for (int kk = 0; kk < 4; ++kk)
                A1[kk] = *(const short8*)(abase + (size_t)(c + 1) * 2048 + kk * 32);
            SCORE_STEP(A0);
            if (c + 2 < c1) {
                #pragma unroll
                for (int kk = 0; kk < 4; ++kk)
                    A0[kk] = *(const short8*)(abase + (size_t)(c + 2) * 2048 + kk * 32);
            }
            SCORE_STEP(A1);
        }
        if (c < c1) SCORE_STEP(A0);

        acc0 += __shfl_xor(acc0, 16, 64); acc0 += __shfl_xor(acc0, 32, 64);
        acc1 += __shfl_xor(acc1, 16, 64); acc1 += __shfl_xor(acc1, 32, 64);
        acc2 += __shfl_xor(acc2, 16, 64); acc2 += __shfl_xor(acc2, 32, 64);
        acc3 += __shfl_xor(acc3, 16, 64); acc3 += __shfl_xor(acc3, 32, 64);
        if (quad == 0) {
            atomicAdd(&rowsum[rbase +  0 + col16], acc0);
            atomicAdd(&rowsum[rbase + 16 + col16], acc1);
            atomicAdd(&rowsum[rbase + 32 + col16], acc2);
            atomicAdd(&rowsum[rbase + 48 + col16], acc3);
        }
    }
}

// ---------------- final: loss = sum(log(rowsum) - pos), pos in fp32 ----------------
__global__ __launch_bounds__(256) void final_kernel(
    const float2* __restrict__ u2, const float* __restrict__ ent,
    const int* __restrict__ cidx, const float* __restrict__ rowsum,
    float* __restrict__ out)
{
    int wv = threadIdx.x >> 6, lane = threadIdx.x & 63;
    int row = blockIdx.x * 4 + wv;       // grid 1024 -> 4096 rows
    int ci = cidx[row];
    const float2* tp = (const float2*)(ent + (size_t)(BASE + ci) * DD);
    float2 a = u2[row * 64 + lane];
    float2 t = tp[lane];
    float p = a.x * t.x + a.y * t.y;
    #pragma unroll
    for (int off = 32; off > 0; off >>= 1) p += __shfl_xor(p, off, 64);
    if (lane == 0) atomicAdd(out, logf(rowsum[row]) - p);
}

extern "C" void kernel_launch(void* const* d_in, const int* in_sizes, int n_in,
                              void* d_out, int out_size, void* d_ws, size_t ws_size,
                              hipStream_t stream)
{
    (void)in_sizes; (void)n_in; (void)out_size; (void)ws_size;
    const float* ent   = (const float*)d_in[0];
    const float* query = (const float*)d_in[1];
    const float* rel   = (const float*)d_in[2];
    const int* esrc    = (const int*)d_in[3];
    const int* edst    = (const int*)d_in[4];
    const int* erel    = (const int*)d_in[5];
    const int* seeds   = (const int*)d_in[6];
    const int* cidx    = (const int*)d_in[7];
    float* out = (float*)d_out;

    // ws: node0 | node1 | offs | partials | gcount | bkt | sortedp | vbarr | gath | u | ubf | cb | rowsum
    char* ws = (char*)d_ws;
    size_t off = 0;
    unsigned* node0   = (unsigned*)(ws + off);       off += (size_t)N_ENT * DD * 2;            // 64.0 MB
    unsigned* node1   = (unsigned*)(ws + off);       off += (size_t)N_ENT * DD * 2;            // 64.0 MB
    int*      offs    = (int*)(ws + off);            off += (size_t)T_STEPS * N_PAD * 4;       // 16.1 MB
    int*      partials= (int*)(ws + off);            off += (size_t)T_STEPS * NB * 4;          // 15.7 KB
    int*      gcount  = (int*)(ws + off);            off += (size_t)T_STEPS * NBKT * 4;        // 15.7 KB
    unsigned* bkt     = (unsigned*)(ws + off);       off += (size_t)T_STEPS * NBKT * CAPB * 4; // 24.1 MB
    unsigned* sortedp = (unsigned*)(ws + off);       off += (size_t)T_STEPS * E_EDGES * 4;     // 19.2 MB
    unsigned char* vbarr = (unsigned char*)(ws + off); off += (size_t)T_STEPS * N_PAD;         //  4.0 MB
    float*    gath    = (float*)(ws + off);          off += (size_t)T_STEPS * 5 * S_SEEDS * DD * 4;
    float*    u       = (float*)(ws + off);          off += (size_t)T_STEPS * S_SEEDS * DD * 4;
    unsigned* ubf     = (unsigned*)(ws + off);       off += (size_t)T_STEPS * S_SEEDS * DD * 2;
    unsigned short* cb = (unsigned short*)(ws + off); off += (size_t)C_NUM * DD * 2;
    float*    rsum    = (float*)(ws + off);          off += (size_t)T_STEPS * S_SEEDS * 4;

    int init_items = NODE_W + GC_W + T_STEPS * S_SEEDS + 1;
    init_kernel<<<(init_items + 255) / 256, 256, 0, stream>>>(
        (const float2*)ent, node0, gcount, rsum, out);
    conv_kernel<<<C_NUM * DD / 4 / 256, 256, 0, stream>>>(
        (const float4*)(ent + (size_t)BASE * DD), (ushort4*)cb);

    dim3 bgrid((E_EDGES + EPB - 1) / EPB, T_STEPS);   // (147, 16)
    dim3 kgrid(NBKT, T_STEPS);                        // (245, 16)
    bucketA<<<bgrid, 256, 0, stream>>>(esrc, edst, erel, gcount, bkt);
    histB<<<kgrid, 256, 0, stream>>>(gcount, bkt, offs, partials);
    vb_build<<<(N_ENT + 255) / 256, 256, 0, stream>>>(offs, vbarr);
    scanB_kernel<<<T_STEPS, 256, 0, stream>>>(partials);
    scanC_kernel<<<kgrid, 256, 0, stream>>>(offs, partials, vbarr);
    scatB<<<kgrid, 256, 0, stream>>>(gcount, bkt, offs, vbarr, sortedp);

    for (int t = 0; t < T_STEPS; ++t) {
        gather_fused<<<NGRID16 + SEED16, 256, 0, stream>>>(
            node0, node1, (const float2*)rel, offs, sortedp, seeds, (float2*)gath, t);
    }
    attn_kernel<<<T_STEPS * S_SEEDS, 64, 0, stream>>>(
        (const float2*)query, (const float2*)gath, seeds, (float2*)u, (unsigned*)ubf);
    score_mfma<<<2048, 256, 0, stream>>>((const unsigned short*)ubf, cb, rsum);
    final_kernel<<<T_STEPS * S_SEEDS / 4, 256, 0, stream>>>(
        (const float2*)u, ent, cidx, rsum, out);
}